// Round 1
// 87.133 us; speedup vs baseline: 1.0113x; 1.0113x over previous
//
#include <hip/hip_runtime.h>
#include <hip/hip_bf16.h>
#include <math.h>

#define B_ 2
#define C_ 128
#define H_ 56
#define W_ 56
#define N_ (H_*W_)      // 3136
#define MW_ 28          // W/2

typedef unsigned short ushort_t;
typedef __bf16 v8bf __attribute__((ext_vector_type(8)));
typedef float  v4f  __attribute__((ext_vector_type(4)));

#define MFMA16(a,b,c) __builtin_amdgcn_mfma_f32_16x16x32_bf16((a),(b),(c),0,0,0)

__device__ __forceinline__ unsigned short f2bf(float f) {
    return __builtin_bit_cast(unsigned short, __float2bfloat16(f));
}
__device__ __forceinline__ unsigned int bfpack(float a, float b) {
    return (unsigned int)f2bf(a) | ((unsigned int)f2bf(b) << 16);
}
__device__ __forceinline__ void unpack8(uint4 u, float* f) {
    f[0] = __uint_as_float(u.x << 16); f[1] = __uint_as_float(u.x & 0xffff0000u);
    f[2] = __uint_as_float(u.y << 16); f[3] = __uint_as_float(u.y & 0xffff0000u);
    f[4] = __uint_as_float(u.z << 16); f[5] = __uint_as_float(u.z & 0xffff0000u);
    f[6] = __uint_as_float(u.w << 16); f[7] = __uint_as_float(u.w & 0xffff0000u);
}

// ---- LDS layout (bytes); lifetimes allow aliasing ----
// Wb   @0       34816  [128][136] bf16  (asym chunks, Wq, Wk, Wv, Wo reuse)
// XT   @34816   26112  [96][136]  bf16  x halo rows i-1..i+1, cols j0-1..j0+28
//                                        (ep [128][36]f aliases, oproj epilogue)
// kT   @60928   26112  [96][136]  bf16
// vT   @87040   26112  [96][136]  bf16  (cat [32][264] aliases, phases 1-2)
// qT   @113152   8704  [32][136]  bf16  (wred [8][32]f aliases, phase 2)
// ao   @121856   8704  [32][136]  bf16
// arow @130560    128  [32]f
#define OFF_W    0
#define OFF_XT   34816
#define OFF_KT   60928
#define OFF_VT   87040
#define OFF_QT   113152
#define OFF_AO   121856
#define OFF_AROW 130560
#define LDS_TOTAL 130688

#define STAGE_W128(SRC) do {                                                  \
    _Pragma("unroll")                                                         \
    for (int it_ = 0; it_ < 8; ++it_) {                                       \
        int idx_ = t + it_ * 512;                                             \
        int row_ = idx_ >> 5, f4_ = idx_ & 31;                                \
        float4 w4_ = *(const float4*)((SRC) + (size_t)row_ * C_ + f4_ * 4);   \
        ushort4 p4_ = { f2bf(w4_.x), f2bf(w4_.y), f2bf(w4_.z), f2bf(w4_.w) }; \
        *(ushort4*)(Wb + row_ * 136 + f4_ * 4) = p4_;                         \
    } } while (0)

// ---------------------------------------------------------------------------
// Fully fused: per block = one (batch, row, half-row) -> qkv (halo recompute),
// 3x3 attention, asym MLP gate (full row), gating, oproj. No workspace.
// ---------------------------------------------------------------------------
__global__ __launch_bounds__(512, 2)
void fused_kernel(const float* __restrict__ x,
                  const float* __restrict__ Wq, const float* __restrict__ Wk,
                  const float* __restrict__ Wv, const float* __restrict__ Wo,
                  const float* __restrict__ bo,
                  const float* __restrict__ Wa1, const float* __restrict__ ba1,
                  const float* __restrict__ Wa2, const float* __restrict__ ba2,
                  float* __restrict__ out) {
    extern __shared__ __align__(16) char smem[];
    ushort_t* Wb   = (ushort_t*)(smem + OFF_W);
    ushort_t* XT   = (ushort_t*)(smem + OFF_XT);
    ushort_t* kT   = (ushort_t*)(smem + OFF_KT);
    ushort_t* vT   = (ushort_t*)(smem + OFF_VT);
    ushort_t* qT   = (ushort_t*)(smem + OFF_QT);
    ushort_t* ao   = (ushort_t*)(smem + OFF_AO);
    ushort_t* cat  = (ushort_t*)(smem + OFF_VT);   // alias: dead before vT written
    float*    wred = (float*)(smem + OFF_QT);      // alias: dead before qT written
    float*    arow = (float*)(smem + OFF_AROW);
    float*    ep   = (float*)(smem + OFF_XT);      // alias: XT dead after qkv

    const int t  = threadIdx.x;
    const int i  = blockIdx.x;           // image row
    const int j0 = blockIdx.y * MW_;     // 0 or 28
    const int b  = blockIdx.z;
    const float* xb = x + (size_t)b * C_ * N_;

    const int w  = t >> 6;               // wave 0..7
    const int l  = t & 63;
    const int lr = l & 15;
    const int lq = l >> 4;

    // ---------------- phase 1: stage x halo (bf16) + cat for asym ------------
    {
        const int col = t & 31, chg = t >> 5;        // chg 0..15
        if (col < 30) {
            const int cjc = min(max(j0 - 1 + col, 0), W_ - 1);
            #pragma unroll
            for (int r = 0; r < 3; ++r) {
                const int ric = min(max(i - 1 + r, 0), H_ - 1);
                const float* src = xb + ric * W_ + cjc;
                float f[8];
                #pragma unroll
                for (int u = 0; u < 8; ++u)
                    f[u] = src[(size_t)(chg * 8 + u) * N_];
                uint4 o;
                o.x = bfpack(f[0], f[1]); o.y = bfpack(f[2], f[3]);
                o.z = bfpack(f[4], f[5]); o.w = bfpack(f[6], f[7]);
                *(uint4*)(XT + (r * 30 + col) * 136 + chg * 8) = o;
            }
        }
        if (col < MW_) {
            const int scol = (chg >= 8) ? (W_ - 1 - col) : col;  // mirrored half
            const float* src = xb + (size_t)((chg & 7) * 16) * N_ + i * W_ + scol;
            float f[16];
            #pragma unroll
            for (int u = 0; u < 16; ++u)
                f[u] = src[(size_t)u * N_];
            uint4 o0, o1;
            o0.x = bfpack(f[0], f[1]);  o0.y = bfpack(f[2], f[3]);
            o0.z = bfpack(f[4], f[5]);  o0.w = bfpack(f[6], f[7]);
            o1.x = bfpack(f[8], f[9]);  o1.y = bfpack(f[10], f[11]);
            o1.z = bfpack(f[12], f[13]); o1.w = bfpack(f[14], f[15]);
            *(uint4*)(cat + col * 264 + chg * 16 + 0) = o0;
            *(uint4*)(cat + col * 264 + chg * 16 + 8) = o1;
        }
    }
    __syncthreads();

    // ---------------- phase 2: asym MLP gate for all 28 positions of row i ---
    v4f acc_a[2];
    acc_a[0] = (v4f){0.f, 0.f, 0.f, 0.f};
    acc_a[1] = (v4f){0.f, 0.f, 0.f, 0.f};
    #pragma unroll
    for (int kc = 0; kc < 2; ++kc) {
        if (kc) __syncthreads();         // Wb reads of previous chunk done
        #pragma unroll
        for (int it = 0; it < 8; ++it) {
            int idx = t + it * 512;
            int row = idx >> 5, f4 = idx & 31;
            float4 w4 = *(const float4*)(Wa1 + (size_t)row * 256 + kc * 128 + f4 * 4);
            ushort4 p4 = { f2bf(w4.x), f2bf(w4.y), f2bf(w4.z), f2bf(w4.w) };
            *(ushort4*)(Wb + row * 136 + f4 * 4) = p4;
        }
        __syncthreads();
        #pragma unroll
        for (int ks = 0; ks < 4; ++ks) {
            v8bf af = *(const v8bf*)(Wb + (w * 16 + lr) * 136 + ks * 32 + lq * 8);
            #pragma unroll
            for (int nt = 0; nt < 2; ++nt) {
                v8bf bfr = *(const v8bf*)(cat + (nt * 16 + lr) * 264 + kc * 128 + ks * 32 + lq * 8);
                acc_a[nt] = MFMA16(af, bfr, acc_a[nt]);
            }
        }
    }
    {
        float p2[2] = {0.f, 0.f};
        #pragma unroll
        for (int r = 0; r < 4; ++r) {
            int m = w * 16 + lq * 4 + r;
            float wa2v = Wa2[m], b1v = ba1[m];
            #pragma unroll
            for (int nt = 0; nt < 2; ++nt) {
                float val = acc_a[nt][r] + b1v;
                float gl = 0.5f * val * (1.0f + erff(val * 0.7071067811865475f));
                p2[nt] += gl * wa2v;
            }
        }
        #pragma unroll
        for (int nt = 0; nt < 2; ++nt) {
            p2[nt] += __shfl_xor(p2[nt], 16, 64);
            p2[nt] += __shfl_xor(p2[nt], 32, 64);
        }
        if (l < 16) {
            wred[w * 32 + lr]      = p2[0];
            wred[w * 32 + 16 + lr] = p2[1];
        }
    }
    __syncthreads();     // wred visible; also all asym MFMA Wb/cat reads done
    if (t < 32) {
        float s = ba2[0];
        #pragma unroll
        for (int ww = 0; ww < 8; ++ww) s += wred[ww * 32 + t];
        arow[t] = 1.0f / (1.0f + expf(-s));   // positions 28..31 unused garbage
    }
    // (arow readers are behind multiple later barriers)

    // ---------------- phase 3: q/k/v projections into LDS --------------------
    // q: only the 28 center pixels (halo slots 31..58 -> padded 2 n-tiles)
    STAGE_W128(Wq);
    __syncthreads();
    {
        v4f acc[2];
        acc[0] = (v4f){0.f, 0.f, 0.f, 0.f};
        acc[1] = (v4f){0.f, 0.f, 0.f, 0.f};
        #pragma unroll
        for (int ks = 0; ks < 4; ++ks) {
            v8bf af = *(const v8bf*)(Wb + (w * 16 + lr) * 136 + ks * 32 + lq * 8);
            #pragma unroll
            for (int nt = 0; nt < 2; ++nt) {
                v8bf bfr = *(const v8bf*)(XT + (31 + nt * 16 + lr) * 136 + ks * 32 + lq * 8);
                acc[nt] = MFMA16(af, bfr, acc[nt]);
            }
        }
        #pragma unroll
        for (int nt = 0; nt < 2; ++nt) {
            uint2 pk;
            pk.x = bfpack(acc[nt][0], acc[nt][1]);
            pk.y = bfpack(acc[nt][2], acc[nt][3]);
            *(uint2*)(qT + (nt * 16 + lr) * 136 + w * 16 + lq * 4) = pk;
        }
    }
    __syncthreads();
    // k: all 90 halo slots (pad to 96)
    STAGE_W128(Wk);
    __syncthreads();
    {
        v4f acc[6];
        #pragma unroll
        for (int nt = 0; nt < 6; ++nt) acc[nt] = (v4f){0.f, 0.f, 0.f, 0.f};
        #pragma unroll
        for (int ks = 0; ks < 4; ++ks) {
            v8bf af = *(const v8bf*)(Wb + (w * 16 + lr) * 136 + ks * 32 + lq * 8);
            #pragma unroll
            for (int nt = 0; nt < 6; ++nt) {
                v8bf bfr = *(const v8bf*)(XT + (nt * 16 + lr) * 136 + ks * 32 + lq * 8);
                acc[nt] = MFMA16(af, bfr, acc[nt]);
            }
        }
        #pragma unroll
        for (int nt = 0; nt < 6; ++nt) {
            uint2 pk;
            pk.x = bfpack(acc[nt][0], acc[nt][1]);
            pk.y = bfpack(acc[nt][2], acc[nt][3]);
            *(uint2*)(kT + (nt * 16 + lr) * 136 + w * 16 + lq * 4) = pk;
        }
    }
    __syncthreads();
    // v
    STAGE_W128(Wv);
    __syncthreads();
    {
        v4f acc[6];
        #pragma unroll
        for (int nt = 0; nt < 6; ++nt) acc[nt] = (v4f){0.f, 0.f, 0.f, 0.f};
        #pragma unroll
        for (int ks = 0; ks < 4; ++ks) {
            v8bf af = *(const v8bf*)(Wb + (w * 16 + lr) * 136 + ks * 32 + lq * 8);
            #pragma unroll
            for (int nt = 0; nt < 6; ++nt) {
                v8bf bfr = *(const v8bf*)(XT + (nt * 16 + lr) * 136 + ks * 32 + lq * 8);
                acc[nt] = MFMA16(af, bfr, acc[nt]);
            }
        }
        #pragma unroll
        for (int nt = 0; nt < 6; ++nt) {
            uint2 pk;
            pk.x = bfpack(acc[nt][0], acc[nt][1]);
            pk.y = bfpack(acc[nt][2], acc[nt][3]);
            *(uint2*)(vT + (nt * 16 + lr) * 136 + w * 16 + lq * 4) = pk;
        }
    }
    __syncthreads();

    // ---------------- phase 4: Wo staging (overlaps attention) + attention ---
    STAGE_W128(Wo);   // Wb free during attention; latency hides under attention
    if (t < 448) {    // 28 px x 4 heads x 4 dim-slices, waves 0..6 fully active
        const int jl = t >> 4, head = (t >> 2) & 3, s = t & 3;
        const int j  = j0 + jl;
        const int dbase = head * 32 + s * 8;

        float qf[8];
        unpack8(*(const uint4*)(qT + jl * 136 + dbase), qf);

        float dts[9]; int sl9[9];
        #pragma unroll
        for (int tt = 0; tt < 9; ++tt) {
            int di = tt / 3 - 1, dj = tt % 3 - 1;
            int ii = i + di, jj = j + dj;
            bool ok = ((unsigned)ii < (unsigned)H_) && ((unsigned)jj < (unsigned)W_);
            int slot = (di + 1) * 30 + (jl + dj + 1);
            sl9[tt] = slot;
            float kf[8];
            unpack8(*(const uint4*)(kT + slot * 136 + dbase), kf);
            float pd = qf[0]*kf[0] + qf[1]*kf[1] + qf[2]*kf[2] + qf[3]*kf[3]
                     + qf[4]*kf[4] + qf[5]*kf[5] + qf[6]*kf[6] + qf[7]*kf[7];
            pd += __shfl_xor(pd, 1, 64);
            pd += __shfl_xor(pd, 2, 64);
            dts[tt] = ok ? pd * 0.17677669529663687f : -1e30f;   // 1/sqrt(32)
        }
        float mx = dts[0];
        #pragma unroll
        for (int tt = 1; tt < 9; ++tt) mx = fmaxf(mx, dts[tt]);
        float sum = 0.f;
        #pragma unroll
        for (int tt = 0; tt < 9; ++tt) { dts[tt] = expf(dts[tt] - mx); sum += dts[tt]; }
        const float inv = 1.0f / sum;

        float acc[8] = {0,0,0,0,0,0,0,0};
        #pragma unroll
        for (int tt = 0; tt < 9; ++tt) {
            float vf[8];
            unpack8(*(const uint4*)(vT + sl9[tt] * 136 + dbase), vf);
            float wt = dts[tt] * inv;
            #pragma unroll
            for (int d = 0; d < 8; ++d) acc[d] += wt * vf[d];
        }

        // asym: linear 28->56 (half-pixel centers, clamped edges)
        float f = 0.5f * (float)j - 0.25f;
        f = fminf(fmaxf(f, 0.0f), 27.0f);
        int i0 = (int)f; if (i0 > 26) i0 = 26;
        float frac = f - (float)i0;
        float a = arow[i0] * (1.0f - frac) + arow[i0 + 1] * frac;
        float sc = 1.0f + 0.5f * a;

        uint4 o;
        o.x = bfpack(acc[0] * sc, acc[1] * sc);
        o.y = bfpack(acc[2] * sc, acc[3] * sc);
        o.z = bfpack(acc[4] * sc, acc[5] * sc);
        o.w = bfpack(acc[6] * sc, acc[7] * sc);
        *(uint4*)(ao + jl * 136 + dbase) = o;
    }
    __syncthreads();

    // ---------------- phase 5: oproj + epilogue ------------------------------
    {
        v4f acc[2];
        acc[0] = (v4f){0.f, 0.f, 0.f, 0.f};
        acc[1] = (v4f){0.f, 0.f, 0.f, 0.f};
        #pragma unroll
        for (int ks = 0; ks < 4; ++ks) {
            v8bf af = *(const v8bf*)(Wb + (w * 16 + lr) * 136 + ks * 32 + lq * 8);
            #pragma unroll
            for (int nt = 0; nt < 2; ++nt) {
                v8bf bfr = *(const v8bf*)(ao + (nt * 16 + lr) * 136 + ks * 32 + lq * 8);
                acc[nt] = MFMA16(af, bfr, acc[nt]);
            }
        }
        // ep aliases XT (dead since phase 3); no barrier needed before writes
        float4 bv = *(const float4*)(bo + w * 16 + lq * 4);
        const float bvr[4] = { bv.x, bv.y, bv.z, bv.w };
        #pragma unroll
        for (int nt = 0; nt < 2; ++nt)
            #pragma unroll
            for (int r = 0; r < 4; ++r)
                ep[(w * 16 + lq * 4 + r) * 36 + nt * 16 + lr] = acc[nt][r] + bvr[r];
    }
    __syncthreads();
    #pragma unroll
    for (int it = 0; it < 2; ++it) {
        int idx = t + it * 512;              // 128 ch x 8 quad-slots
        int ch = idx >> 3, q4 = idx & 7;
        if (q4 < 7) {                        // px 0..27
            *(float4*)(out + ((size_t)b * C_ + ch) * N_ + i * W_ + j0 + q4 * 4) =
                *(const float4*)(ep + ch * 36 + q4 * 4);
        }
    }
}

// ---------------------------------------------------------------------------
extern "C" void kernel_launch(void* const* d_in, const int* in_sizes, int n_in,
                              void* d_out, int out_size, void* d_ws, size_t ws_size,
                              hipStream_t stream) {
    (void)in_sizes; (void)n_in; (void)out_size; (void)d_ws; (void)ws_size;
    const float* x   = (const float*)d_in[0];
    const float* Wq  = (const float*)d_in[1];
    const float* Wk  = (const float*)d_in[2];
    const float* Wv  = (const float*)d_in[3];
    const float* Wo  = (const float*)d_in[4];
    const float* bo  = (const float*)d_in[5];
    const float* Wa1 = (const float*)d_in[6];
    const float* ba1 = (const float*)d_in[7];
    const float* Wa2 = (const float*)d_in[8];
    const float* ba2 = (const float*)d_in[9];
    float* out = (float*)d_out;

    static int cfg = 0;
    if (!cfg) {
        hipFuncSetAttribute((const void*)fused_kernel,
                            hipFuncAttributeMaxDynamicSharedMemorySize, LDS_TOTAL);
        cfg = 1;
    }
    fused_kernel<<<dim3(H_, 2, B_), 512, LDS_TOTAL, stream>>>(
        x, Wq, Wk, Wv, Wo, bo, Wa1, ba1, Wa2, ba2, out);
}